// Round 1
// baseline (767.273 us; speedup 1.0000x reference)
//
#include <hip/hip_runtime.h>

// LSTM layer: B=256, T=512, I=64, H=128 (4H = 512 gates), fp32.
// Strategy: one persistent workgroup per batch row (256 blocks = 1/CU).
// 512 threads/block; thread g owns gate row g with its weights register-resident
// (W_hh[g][0:128] + W_ih[g][0:64] = 192 VGPRs). Per step: GEMV via LDS
// broadcast of h/x against register weights; gates exchanged through LDS;
// 128 "j-threads" update c/h and stream h to global.

#define BB 256
#define TT 512
#define II 64
#define HH 128
#define NG 512  // 4*H gate rows

__global__ __launch_bounds__(512, 2)
void lstm_persistent(const float* __restrict__ inputs,   // [B,T,I]
                     const float* __restrict__ h_prev,   // [B,H]
                     const float* __restrict__ c_prev,   // [B,H]
                     const float* __restrict__ W_ih,     // [4H,I]
                     const float* __restrict__ W_hh,     // [4H,H]
                     const float* __restrict__ b_ih,     // [4H]
                     const float* __restrict__ b_hh,     // [4H]
                     float* __restrict__ out)            // outputs|h_last|c_last
{
    const int b   = blockIdx.x;
    const int tid = threadIdx.x;   // gate row index g = tid

    // ---- load weights into registers (one-time; served by L2/L3 after warmup)
    float whh[HH];
    float wih[II];
    {
        const float4* wh4 = (const float4*)(W_hh + (size_t)tid * HH);
        #pragma unroll
        for (int k = 0; k < HH / 4; ++k) {
            float4 v = wh4[k];
            whh[4*k+0] = v.x; whh[4*k+1] = v.y; whh[4*k+2] = v.z; whh[4*k+3] = v.w;
        }
        const float4* wi4 = (const float4*)(W_ih + (size_t)tid * II);
        #pragma unroll
        for (int k = 0; k < II / 4; ++k) {
            float4 v = wi4[k];
            wih[4*k+0] = v.x; wih[4*k+1] = v.y; wih[4*k+2] = v.z; wih[4*k+3] = v.w;
        }
    }
    const float bias = b_ih[tid] + b_hh[tid];

    __shared__ __align__(16) float h_lds[2][HH];
    __shared__ __align__(16) float x_lds[2][II];
    __shared__ __align__(16) float gates_lds[NG];

    // ---- init recurrent state
    float c = 0.f, h = 0.f;
    if (tid < HH) {
        c = c_prev[(size_t)b * HH + tid];
        h = h_prev[(size_t)b * HH + tid];
        h_lds[0][tid] = h;
    }
    const float* xin = inputs + (size_t)b * TT * II;
    if (tid < II) x_lds[0][tid] = xin[tid];
    __syncthreads();

    float* outp = out + (size_t)b * TT * HH;
    int cur = 0;

    for (int t = 0; t < TT; ++t) {
        // prefetch next timestep's x into registers (latency hidden by GEMV)
        float xpre = 0.f;
        const int tn = (t + 1 < TT) ? (t + 1) : (TT - 1);
        if (tid < II) xpre = xin[(size_t)tn * II + tid];

        // ---- gate pre-activation: bias + W_ih[g]·x[t] + W_hh[g]·h
        float acc = bias;
        const float4* xl = (const float4*)x_lds[t & 1];
        #pragma unroll
        for (int k = 0; k < II / 4; ++k) {
            float4 v = xl[k];   // wave-broadcast read, conflict-free
            acc = fmaf(wih[4*k+0], v.x, acc);
            acc = fmaf(wih[4*k+1], v.y, acc);
            acc = fmaf(wih[4*k+2], v.z, acc);
            acc = fmaf(wih[4*k+3], v.w, acc);
        }
        const float4* hl = (const float4*)h_lds[cur];
        #pragma unroll
        for (int k = 0; k < HH / 4; ++k) {
            float4 v = hl[k];   // wave-broadcast read, conflict-free
            acc = fmaf(whh[4*k+0], v.x, acc);
            acc = fmaf(whh[4*k+1], v.y, acc);
            acc = fmaf(whh[4*k+2], v.z, acc);
            acc = fmaf(whh[4*k+3], v.w, acc);
        }

        // ---- activation (wave-uniform branch: gate type = tid>>7)
        float a;
        if ((tid >> 7) == 2) {
            a = tanhf(acc);                       // cell gate
        } else {
            a = 1.0f / (1.0f + __expf(-acc));     // i/f/o gates
        }
        gates_lds[tid] = a;
        __syncthreads();

        // ---- state update on j-threads; stream h to global
        if (tid < HH) {
            float ig = gates_lds[tid];
            float fg = gates_lds[tid + HH];
            float gg = gates_lds[tid + 2 * HH];
            float og = gates_lds[tid + 3 * HH];
            c = fmaf(fg, c, ig * gg);
            h = og * tanhf(c);
            h_lds[cur ^ 1][tid] = h;
            outp[(size_t)t * HH + tid] = h;
        }
        if (tid < II) x_lds[(t + 1) & 1][tid] = xpre;
        __syncthreads();
        cur ^= 1;
    }

    // ---- h_last, c_last
    if (tid < HH) {
        out[(size_t)BB * TT * HH + (size_t)b * HH + tid] = h;
        out[(size_t)BB * TT * HH + (size_t)BB * HH + (size_t)b * HH + tid] = c;
    }
}

extern "C" void kernel_launch(void* const* d_in, const int* in_sizes, int n_in,
                              void* d_out, int out_size, void* d_ws, size_t ws_size,
                              hipStream_t stream) {
    const float* inputs = (const float*)d_in[0];
    const float* h_prev = (const float*)d_in[1];
    const float* c_prev = (const float*)d_in[2];
    const float* W_ih   = (const float*)d_in[3];
    const float* W_hh   = (const float*)d_in[4];
    const float* b_ih   = (const float*)d_in[5];
    const float* b_hh   = (const float*)d_in[6];
    float* outp = (float*)d_out;

    lstm_persistent<<<dim3(BB), dim3(NG), 0, stream>>>(
        inputs, h_prev, c_prev, W_ih, W_hh, b_ih, b_hh, outp);
}

// Round 2
// 547.286 us; speedup vs baseline: 1.4020x; 1.4020x over previous
//
#include <hip/hip_runtime.h>

// LSTM B=256,T=512,I=64,H=128 fp32. R2 restructure:
// - 256 blocks (1/CU) x 1024 threads (16 waves/CU = 50% occ cap).
// - thread = (j, ks): h-column j in [0,128), k-slice ks in [0,8).
//   Owns 4 gate rows {j, j+128, j+256, j+384} (i,f,g,o) x 24 k -> 96 weight
//   floats register-resident (1024-thr block caps VGPR at 128; 96+state fits,
//   unlike R1's 192 which the compiler refused and rematerialized -> VGPR=120).
// - x(t) and h(t) unified in xh[192] LDS, double-buffered, ONE barrier/step.
// - 8 k-slice partials butterfly-reduced via DPP xor1/xor2 + ds_swizzle xor4;
//   every lane gets all 4 gates for column j -> c,h update in registers,
//   no gates LDS round-trip.

#define BB 256
#define TT 512
#define II 64
#define HH 128
#define KK 192          // II + HH unified K
#define KS 8            // k-split factor
#define KPT (KK / KS)   // 24 k per thread
#define NTH (HH * KS)   // 1024 threads

static_assert(KPT % 4 == 0, "float4 granularity");

__device__ __forceinline__ float dpp_xor1(float v) {
    return __int_as_float(__builtin_amdgcn_mov_dpp(__float_as_int(v), 0xB1, 0xF, 0xF, true)); // quad_perm {1,0,3,2}
}
__device__ __forceinline__ float dpp_xor2(float v) {
    return __int_as_float(__builtin_amdgcn_mov_dpp(__float_as_int(v), 0x4E, 0xF, 0xF, true)); // quad_perm {2,3,0,1}
}
__device__ __forceinline__ float swz_xor4(float v) {
    return __int_as_float(__builtin_amdgcn_ds_swizzle(__float_as_int(v), 0x101F)); // xor_mask=4
}
__device__ __forceinline__ float fast_sigmoid(float x) {
    float e = __expf(-x);
    return __builtin_amdgcn_rcpf(1.0f + e);
}
__device__ __forceinline__ float fast_tanh(float x) {
    float e = __expf(2.0f * x);                       // +inf ok -> rcp -> 0 -> 1
    return 1.0f - 2.0f * __builtin_amdgcn_rcpf(e + 1.0f);
}

__global__ __launch_bounds__(NTH, 4)
void lstm_split(const float* __restrict__ inputs,   // [B,T,I]
                const float* __restrict__ h_prev,   // [B,H]
                const float* __restrict__ c_prev,   // [B,H]
                const float* __restrict__ W_ih,     // [4H,I]
                const float* __restrict__ W_hh,     // [4H,H]
                const float* __restrict__ b_ih,     // [4H]
                const float* __restrict__ b_hh,     // [4H]
                float* __restrict__ out)            // outputs|h_last|c_last
{
    const int b   = blockIdx.x;
    const int tid = threadIdx.x;
    const int j   = tid >> 3;     // h column
    const int ks  = tid & 7;      // k slice
    const int k0  = ks * KPT;

    // ---- register-resident weights: unified k axis {W_ih row | W_hh row}
    float w[4][KPT];
    #pragma unroll
    for (int r = 0; r < 4; ++r) {
        const int row = j + r * HH;
        #pragma unroll
        for (int g = 0; g < KPT / 4; ++g) {
            const int k = k0 + 4 * g;
            float4 v = (k < II) ? *(const float4*)(W_ih + (size_t)row * II + k)
                                : *(const float4*)(W_hh + (size_t)row * HH + (k - II));
            w[r][4*g+0] = v.x; w[r][4*g+1] = v.y; w[r][4*g+2] = v.z; w[r][4*g+3] = v.w;
        }
    }
    // bias contributed by the ks==0 lane only (post-reduction sum gets it once)
    float bias[4];
    #pragma unroll
    for (int r = 0; r < 4; ++r) {
        const int row = j + r * HH;
        bias[r] = (ks == 0) ? (b_ih[row] + b_hh[row]) : 0.0f;
    }

    __shared__ __align__(16) float xh[2][KK];   // [x(64) | h(128)] double-buffered

    float c = c_prev[(size_t)b * HH + j];       // replicated across 8 ks-lanes
    float h = 0.0f;

    const float* xin = inputs + (size_t)b * TT * II;
    if (ks == 0) xh[0][II + j] = h_prev[(size_t)b * HH + j];
    if (tid < II) xh[0][tid] = xin[tid];
    __syncthreads();

    float* outp = out + (size_t)b * TT * HH;
    float* cur = xh[0];
    float* nxt = xh[1];

    for (int t = 0; t < TT; ++t) {
        // prefetch next x into regs (latency hidden under GEMV)
        float xpre = 0.0f;
        if (tid < II) {
            const int tn = (t + 1 < TT) ? (t + 1) : (TT - 1);
            xpre = xin[(size_t)tn * II + tid];
        }

        // ---- 96 FMAs: 4 gate rows x 24 k, 4 independent chains (len 24)
        float a0 = bias[0], a1 = bias[1], a2 = bias[2], a3 = bias[3];
        const float4* xc = (const float4*)(cur + k0);
        #pragma unroll
        for (int g = 0; g < KPT / 4; ++g) {
            const float4 v = xc[g];   // 8 distinct addrs/wave, 2-way bank alias = free
            a0 = fmaf(w[0][4*g+0], v.x, a0); a1 = fmaf(w[1][4*g+0], v.x, a1);
            a2 = fmaf(w[2][4*g+0], v.x, a2); a3 = fmaf(w[3][4*g+0], v.x, a3);
            a0 = fmaf(w[0][4*g+1], v.y, a0); a1 = fmaf(w[1][4*g+1], v.y, a1);
            a2 = fmaf(w[2][4*g+1], v.y, a2); a3 = fmaf(w[3][4*g+1], v.y, a3);
            a0 = fmaf(w[0][4*g+2], v.z, a0); a1 = fmaf(w[1][4*g+2], v.z, a1);
            a2 = fmaf(w[2][4*g+2], v.z, a2); a3 = fmaf(w[3][4*g+2], v.z, a3);
            a0 = fmaf(w[0][4*g+3], v.w, a0); a1 = fmaf(w[1][4*g+3], v.w, a1);
            a2 = fmaf(w[2][4*g+3], v.w, a2); a3 = fmaf(w[3][4*g+3], v.w, a3);
        }

        // ---- butterfly over the 8 ks-lanes (lanes j*8+ks, xor {1,2,4})
        a0 += dpp_xor1(a0); a0 += dpp_xor2(a0); a0 += swz_xor4(a0);
        a1 += dpp_xor1(a1); a1 += dpp_xor2(a1); a1 += swz_xor4(a1);
        a2 += dpp_xor1(a2); a2 += dpp_xor2(a2); a2 += swz_xor4(a2);
        a3 += dpp_xor1(a3); a3 += dpp_xor2(a3); a3 += swz_xor4(a3);

        // ---- gates + state update, all lanes redundantly (no divergence)
        const float ig = fast_sigmoid(a0);
        const float fg = fast_sigmoid(a1);
        const float gg = fast_tanh(a2);
        const float og = fast_sigmoid(a3);
        c = fmaf(fg, c, ig * gg);
        h = og * fast_tanh(c);

        if (ks == 0) {
            nxt[II + j] = h;
            outp[(size_t)t * HH + j] = h;
        }
        if (tid < II) nxt[tid] = xpre;
        __syncthreads();                 // single barrier per step
        float* tmp = cur; cur = nxt; nxt = tmp;
    }

    if (ks == 0) {
        out[(size_t)BB * TT * HH + (size_t)b * HH + j] = h;
        out[(size_t)BB * TT * HH + (size_t)BB * HH + (size_t)b * HH + j] = c;
    }
}

extern "C" void kernel_launch(void* const* d_in, const int* in_sizes, int n_in,
                              void* d_out, int out_size, void* d_ws, size_t ws_size,
                              hipStream_t stream) {
    const float* inputs = (const float*)d_in[0];
    const float* h_prev = (const float*)d_in[1];
    const float* c_prev = (const float*)d_in[2];
    const float* W_ih   = (const float*)d_in[3];
    const float* W_hh   = (const float*)d_in[4];
    const float* b_ih   = (const float*)d_in[5];
    const float* b_hh   = (const float*)d_in[6];
    float* outp = (float*)d_out;

    lstm_split<<<dim3(BB), dim3(NTH), 0, stream>>>(
        inputs, h_prev, c_prev, W_ih, W_hh, b_ih, b_hh, outp);
}